// Round 3
// baseline (206.454 us; speedup 1.0000x reference)
//
#include <hip/hip_runtime.h>

// CSPN step: out[b,h,w] = sum_{t=0..8} patch_t(b,h,w) * kernel[b,t,h,w]
// patch taps = zero-padded 3x3 neighborhood of input; center tap (t=4)
// replaced by input0. iter_weight is unused (reference returns cspn_output).
//
// Shapes: kernel (8,9,352,1216) f32, input/input0 (8,1,352,1216) f32.
// Memory-bound: ~150.6 MB read + 13.7 MB write -> ~26 us floor at 6.3 TB/s.
//
// R1/R2: branch-free (clamped offsets + multiplicative pad masks) so all 24
// VMEM loads issue before the first wait; 8 px/thread; nontemporal on the
// zero-reuse kernel stream + output store (via ext_vector_type — HIP float4
// is a class and the builtin rejects it), cached path for reused input rows.

#define BS 8
#define H  352
#define W  1216
#define HW (H * W)
#define WG (W / 8)   // 152 groups of 8 pixels per row

typedef float vf4 __attribute__((ext_vector_type(4)));

__device__ __forceinline__ vf4 ldnt4(const float* p) {
    return __builtin_nontemporal_load((const vf4*)p);
}

__global__ __launch_bounds__(256) void cspn_kernel(
    const float* __restrict__ kern,
    const float* __restrict__ in,
    const float* __restrict__ in0,
    float* __restrict__ out)
{
    const int total = BS * H * WG;   // 428032
    int idx = blockIdx.x * blockDim.x + threadIdx.x;
    if (idx >= total) return;

    int b   = idx / (H * WG);
    int rem = idx - b * (H * WG);
    int h   = rem / WG;
    int w0  = (rem - h * WG) * 8;

    const float* __restrict__ rowc = in  + (size_t)b * HW + (size_t)h * W + w0;
    const float* __restrict__ zp   = in0 + (size_t)b * HW + (size_t)h * W + w0;
    const float* __restrict__ kb   = kern + (size_t)b * 9 * HW + (size_t)h * W + w0;

    // padding handled branch-free: clamp the address, zero the value
    const float mT = (h > 0)      ? 1.f : 0.f;
    const float mB = (h < H - 1)  ? 1.f : 0.f;
    const ptrdiff_t oT = (h > 0)     ? -(ptrdiff_t)W : 0;
    const ptrdiff_t oB = (h < H - 1) ?  (ptrdiff_t)W : 0;
    const int   oL = (w0 > 0)     ? -1 : 0;
    const int   oR = (w0 + 8 < W) ?  8 : 7;
    const float mL = (w0 > 0)     ? 1.f : 0.f;
    const float mR = (w0 + 8 < W) ? 1.f : 0.f;

    const float* rowt = rowc + oT;
    const float* rowb = rowc + oB;

    // ---- all loads, no branches between them ----
    vf4 t0 = *(const vf4*)(rowt);
    vf4 t1 = *(const vf4*)(rowt + 4);
    float tl = rowt[oL], tr = rowt[oR];
    vf4 c0 = *(const vf4*)(rowc);
    vf4 c1 = *(const vf4*)(rowc + 4);
    float cl = rowc[oL], cr = rowc[oR];
    vf4 bb0 = *(const vf4*)(rowb);
    vf4 bb1 = *(const vf4*)(rowb + 4);
    float bl = rowb[oL], br = rowb[oR];
    vf4 z0 = *(const vf4*)(zp);
    vf4 z1 = *(const vf4*)(zp + 4);

    float kk[9][8];
    #pragma unroll
    for (int t = 0; t < 9; ++t) {
        vf4 ka = ldnt4(kb + (size_t)t * HW);
        vf4 kc = ldnt4(kb + (size_t)t * HW + 4);
        kk[t][0] = ka.x; kk[t][1] = ka.y; kk[t][2] = ka.z; kk[t][3] = ka.w;
        kk[t][4] = kc.x; kk[t][5] = kc.y; kk[t][6] = kc.z; kk[t][7] = kc.w;
    }

    // tap-value rows, 10 wide (left scalar | 8 center | right scalar)
    float vt[10] = {tl * mL, t0.x, t0.y, t0.z, t0.w, t1.x, t1.y, t1.z, t1.w, tr * mR};
    float vc[10] = {cl * mL, c0.x, c0.y, c0.z, c0.w, c1.x, c1.y, c1.z, c1.w, cr * mR};
    float vb[10] = {bl * mL, bb0.x, bb0.y, bb0.z, bb0.w, bb1.x, bb1.y, bb1.z, bb1.w, br * mR};
    float vz[8]  = {z0.x, z0.y, z0.z, z0.w, z1.x, z1.y, z1.z, z1.w};
    #pragma unroll
    for (int i = 0; i < 10; ++i) { vt[i] *= mT; vb[i] *= mB; }

    float acc[8];
    #pragma unroll
    for (int i = 0; i < 8; ++i) {
        acc[i]  = vt[i] * kk[0][i] + vt[i+1] * kk[1][i] + vt[i+2] * kk[2][i];
        acc[i] += vc[i] * kk[3][i] + vz[i]   * kk[4][i] + vc[i+2] * kk[5][i];
        acc[i] += vb[i] * kk[6][i] + vb[i+1] * kk[7][i] + vb[i+2] * kk[8][i];
    }

    float* op = out + (size_t)b * HW + (size_t)h * W + w0;
    vf4 o0 = {acc[0], acc[1], acc[2], acc[3]};
    vf4 o1 = {acc[4], acc[5], acc[6], acc[7]};
    __builtin_nontemporal_store(o0, (vf4*)op);
    __builtin_nontemporal_store(o1, (vf4*)(op + 4));
}

extern "C" void kernel_launch(void* const* d_in, const int* in_sizes, int n_in,
                              void* d_out, int out_size, void* d_ws, size_t ws_size,
                              hipStream_t stream) {
    const float* kern = (const float*)d_in[0];  // (8,9,352,1216)
    // d_in[1] = iter_weight, unused by the reference's return value
    const float* in   = (const float*)d_in[2];  // (8,1,352,1216)
    const float* in0  = (const float*)d_in[3];  // (8,1,352,1216)
    float* out        = (float*)d_out;          // (8,1,352,1216)

    const int total = BS * H * WG;              // 428032 threads
    const int block = 256;
    const int grid  = (total + block - 1) / block;  // 1673
    cspn_kernel<<<grid, block, 0, stream>>>(kern, in, in0, out);
}

// Round 4
// 200.926 us; speedup vs baseline: 1.0275x; 1.0275x over previous
//
#include <hip/hip_runtime.h>

// CSPN step: out[b,h,w] = sum_{t=0..8} patch_t(b,h,w) * kernel[b,t,h,w]
// patch taps = zero-padded 3x3 neighborhood of input; center tap (t=4)
// replaced by input0. iter_weight is unused (reference returns cspn_output).
//
// Shapes: kernel (8,9,352,1216) f32, input/input0 (8,1,352,1216) f32.
// Memory-bound: 123 MB kernel stream (single-use) + ~42 MB in/in0/out
// -> ~25 us floor at achieved fill BW (6.85 TB/s).
//
// R4: revert to R1 structure (4 px/thread, branchy di-loop) — measured best
// (201.2 us vs 206.5 for branch-free/8px/nontemporal). With ~26 waves/CU,
// TLP hides all latency; per-wave load clustering doesn't matter. Kernel is
// HBM-BW-bound on the 9-tap weight stream; bench metric dominated by fixed
// harness reset traffic (~145-170 us of 493 MB ws-poison + input restore).

#define BS 8
#define H  352
#define W  1216
#define HW (H * W)

__global__ __launch_bounds__(256) void cspn_kernel(
    const float* __restrict__ kern,
    const float* __restrict__ in,
    const float* __restrict__ in0,
    float* __restrict__ out)
{
    const int groupsPerImg = HW / 4;        // 107008
    const int total = BS * groupsPerImg;    // 856064
    int idx = blockIdx.x * blockDim.x + threadIdx.x;
    if (idx >= total) return;

    int b   = idx / groupsPerImg;
    int rem = idx - b * groupsPerImg;
    int h   = rem / (W / 4);
    int wg  = rem - h * (W / 4);
    int w0  = wg * 4;

    const float* inb  = in  + (size_t)b * HW;
    const float* in0b = in0 + (size_t)b * HW;
    // kernel base for this (b, h, w0); tap t is +t*HW from here
    const float* kb   = kern + ((size_t)b * 9) * HW + (size_t)h * W + w0;

    float4 acc = {0.f, 0.f, 0.f, 0.f};

    #pragma unroll
    for (int di = -1; di <= 1; ++di) {
        int hh = h + di;
        if (hh < 0 || hh >= H) continue;   // zero-padded rows contribute 0

        const float* row = inb + (size_t)hh * W + w0;
        float4 x   = *(const float4*)row;                 // aligned: w0 % 4 == 0
        float  xm1 = (w0 > 0)     ? row[-1] : 0.f;        // left edge pad
        float  xp4 = (w0 + 4 < W) ? row[4]  : 0.f;        // right edge pad

        // center-column tap values: input0 for di==0 (compile-time after unroll)
        float4 c = x;
        if (di == 0) c = *(const float4*)(in0b + (size_t)h * W + w0);

        float4 l = {xm1, x.x, x.y, x.z};   // tap column j=-1
        float4 r = {x.y, x.z, x.w, xp4};   // tap column j=+1

        int t = (di + 1) * 3;
        float4 k0 = *(const float4*)(kb + (size_t)t       * HW);
        float4 k1 = *(const float4*)(kb + (size_t)(t + 1) * HW);
        float4 k2 = *(const float4*)(kb + (size_t)(t + 2) * HW);

        acc.x += l.x * k0.x + c.x * k1.x + r.x * k2.x;
        acc.y += l.y * k0.y + c.y * k1.y + r.y * k2.y;
        acc.z += l.z * k0.z + c.z * k1.z + r.z * k2.z;
        acc.w += l.w * k0.w + c.w * k1.w + r.w * k2.w;
    }

    *(float4*)(out + (size_t)b * HW + (size_t)h * W + w0) = acc;
}

extern "C" void kernel_launch(void* const* d_in, const int* in_sizes, int n_in,
                              void* d_out, int out_size, void* d_ws, size_t ws_size,
                              hipStream_t stream) {
    const float* kern = (const float*)d_in[0];  // (8,9,352,1216)
    // d_in[1] = iter_weight, unused by the reference's return value
    const float* in   = (const float*)d_in[2];  // (8,1,352,1216)
    const float* in0  = (const float*)d_in[3];  // (8,1,352,1216)
    float* out        = (float*)d_out;          // (8,1,352,1216)

    const int total  = BS * (HW / 4);           // 856064 threads
    const int block  = 256;
    const int grid   = (total + block - 1) / block;  // 3344
    cspn_kernel<<<grid, block, 0, stream>>>(kern, in, in0, out);
}